// Round 1
// baseline (100.331 us; speedup 1.0000x reference)
//
#include <hip/hip_runtime.h>

// Laplacian3D: out[b,c,z,y,w] = sum_{i,d in {1,2,4}} coeff[i][c] * lap_d(x)
// coeff[i][c] = 0.25 * sigmoid(diff_params[i][c])
// lap_d = -6*x + x(z±d) + x(y±d) + x(w±d), zero padding.
// x: (2, 64, 64, 64, 64) fp32.  Thread = 4 contiguous W elements (float4).

#define TOTAL_THREADS (2 * 64 * 64 * 64 * 16)   // 8,388,608
#define NBLOCKS (TOTAL_THREADS / 256)           // 32,768

__global__ __launch_bounds__(256) void lap3d_kernel(
    const float* __restrict__ x, const float* __restrict__ p,
    float* __restrict__ out)
{
    const int t   = blockIdx.x * 256 + threadIdx.x;
    const int wq  = t & 15;          // which float4 within the W row
    const int row = t >> 4;          // flat (b,c,z,y) row index
    const int y   = row & 63;
    const int z   = (row >> 6) & 63;
    const int c   = (row >> 12) & 63;
    const int w0  = wq << 2;

    const float* xrow = x + (row << 6);

    // per-channel coeffs (wave-uniform -> scalar loads)
    const float k1 = 0.25f / (1.0f + expf(-p[c]));
    const float k2 = 0.25f / (1.0f + expf(-p[64 + c]));
    const float k4 = 0.25f / (1.0f + expf(-p[128 + c]));
    const float ksum = k1 + k2 + k4;

    // 12-float register window covering w0-4 .. w0+7 (zero-padded at edges)
    float win[12];
#pragma unroll
    for (int i = 0; i < 12; ++i) win[i] = 0.0f;
    if (w0 >= 4) {
        const float4 v = *(const float4*)(xrow + w0 - 4);
        win[0] = v.x; win[1] = v.y; win[2] = v.z; win[3] = v.w;
    }
    const float4 cv = *(const float4*)(xrow + w0);
    win[4] = cv.x; win[5] = cv.y; win[6] = cv.z; win[7] = cv.w;
    if (w0 < 60) {
        const float4 v = *(const float4*)(xrow + w0 + 4);
        win[8] = v.x; win[9] = v.y; win[10] = v.z; win[11] = v.w;
    }

    // z/y taps per dilation (zero-padded via bounds check)
    float a1[4] = {0, 0, 0, 0}, a2[4] = {0, 0, 0, 0}, a4[4] = {0, 0, 0, 0};
    auto acc = [&](int dz, int dy, float* a) {
        const int zz = z + dz, yy = y + dy;
        if ((unsigned)zz < 64u && (unsigned)yy < 64u) {
            const float4 v = *(const float4*)(xrow + (dz * 64 + dy) * 64 + w0);
            a[0] += v.x; a[1] += v.y; a[2] += v.z; a[3] += v.w;
        }
    };
    acc(-1, 0, a1); acc(1, 0, a1); acc(0, -1, a1); acc(0, 1, a1);
    acc(-2, 0, a2); acc(2, 0, a2); acc(0, -2, a2); acc(0, 2, a2);
    acc(-4, 0, a4); acc(4, 0, a4); acc(0, -4, a4); acc(0, 4, a4);

    float4 o;
    float* op = &o.x;
#pragma unroll
    for (int j = 0; j < 4; ++j) {
        const float s1 = a1[j] + win[3 + j] + win[5 + j];
        const float s2 = a2[j] + win[2 + j] + win[6 + j];
        const float s4 = a4[j] + win[j]     + win[8 + j];
        op[j] = -6.0f * ksum * win[4 + j] + k1 * s1 + k2 * s2 + k4 * s4;
    }
    *(float4*)(out + (row << 6) + w0) = o;
}

extern "C" void kernel_launch(void* const* d_in, const int* in_sizes, int n_in,
                              void* d_out, int out_size, void* d_ws, size_t ws_size,
                              hipStream_t stream) {
    const float* x = (const float*)d_in[0];
    const float* p = (const float*)d_in[1];
    float* out = (float*)d_out;
    lap3d_kernel<<<NBLOCKS, 256, 0, stream>>>(x, p, out);
}